// Round 1
// baseline (362.777 us; speedup 1.0000x reference)
//
#include <hip/hip_runtime.h>
#include <math.h>

#define N 512
#define CS 384
#define CZ 128
#define NH 16
#define DH 24
#define HD 384
#define NN (N*N)
#define EPS 1e-5f

// ws layout (float offsets)
#define OFF_AN   0          // a_n [N][CS]
#define OFF_QT   196608     // qT [H][N][D] (pre-scaled by 1/sqrt(24))
#define OFF_KT   393216     // kT [H][N][D]
#define OFF_VT   589824     // vT [H][N][D]
#define OFF_GT   786432     // gT [H][N][D] (sigmoid applied)
#define OFF_OG   983040     // o*g [N][HD]
#define OFF_WZ2  1179648    // g_z*Wz transposed [H][CZ]
#define OFF_SH   1181696    // [H]
#define OFF_BH   1181712    // [H]
#define OFF_BIAS 1181728    // pair bias [H][N][N]

// ---------------- fused: prep (block 256) + LayerNorm of a (blocks 0..255, 2 rows each) ----------------
__global__ void __launch_bounds__(256) ln_prep_kernel(const float* __restrict__ a, const float* __restrict__ g_a,
                                                      const float* __restrict__ b_a, float* __restrict__ an_out,
                                                      const float* __restrict__ g_z, const float* __restrict__ lnb_z,
                                                      const float* __restrict__ Wz, const float* __restrict__ bz,
                                                      float* __restrict__ wz2, float* __restrict__ sh,
                                                      float* __restrict__ bh) {
    __shared__ float ls[NH][17], lb[NH][17];   // prep block
    __shared__ float l1[4], l2[4];             // ln blocks
    const int t = threadIdx.x;
    if (blockIdx.x == 256) {
        // prep: Wz2[h][c] = g_z[c]*Wz[c][h]; Sh, Bh
        for (int i = t; i < NH * CZ; i += 256) {
            int h = i >> 7, c = i & (CZ - 1);
            wz2[h * CZ + c] = g_z[c] * Wz[c * NH + h];
        }
        int h = t >> 4, seg = t & 15;
        float s = 0.f, b = 0.f;
        #pragma unroll
        for (int i = 0; i < 8; ++i) {
            int c = seg * 8 + i;
            float w = Wz[c * NH + h];
            s += g_z[c] * w;
            b += lnb_z[c] * w;
        }
        ls[h][seg] = s; lb[h][seg] = b;
        __syncthreads();
        if (t < NH) {
            float ss = 0.f, bb = 0.f;
            #pragma unroll
            for (int i = 0; i < 16; ++i) { ss += ls[t][i]; bb += lb[t][i]; }
            sh[t] = ss;
            bh[t] = bb + bz[t];
        }
        return;
    }
    // LayerNorm: 2 rows per block (threads 0..127 -> row0, 128..255 -> row1)
    const int half = t >> 7;
    const int tr = t & 127;
    const int r = blockIdx.x * 2 + half;
    const float* row = a + r * CS;
    float x0 = row[tr], x1 = row[tr + 128], x2 = row[tr + 256];
    float s1 = x0 + x1 + x2;
    float s2 = x0 * x0 + x1 * x1 + x2 * x2;
    #pragma unroll
    for (int m = 1; m < 64; m <<= 1) {
        s1 += __shfl_xor(s1, m, 64);
        s2 += __shfl_xor(s2, m, 64);
    }
    if ((t & 63) == 0) { l1[t >> 6] = s1; l2[t >> 6] = s2; }
    __syncthreads();
    s1 = l1[half * 2] + l1[half * 2 + 1];
    s2 = l2[half * 2] + l2[half * 2 + 1];
    float mu = s1 * (1.f / CS);
    float var = s2 * (1.f / CS) - mu * mu;
    float rs = rsqrtf(var + EPS);
    float* an = an_out + r * CS;
    an[tr]       = (x0 - mu) * rs * g_a[tr]       + b_a[tr];
    an[tr + 128] = (x1 - mu) * rs * g_a[tr + 128] + b_a[tr + 128];
    an[tr + 256] = (x2 - mu) * rs * g_a[tr + 256] + b_a[tr + 256];
}

// ---------------- fused: qkvg projections (blocks 0..767, 4 cols/thread) + pair bias (blocks 768..1791) ----------------
// qkvg: wid = b*4+w in [0,3072): strip = wid>>3 (0..383), mblock = wid&7. 3072 waves (2x prev occupancy).
// pairbias: row = (b-768)*256 + t, one z-row per lane (memory-bound; overlaps with qkvg's latency-bound waves).
__global__ void __launch_bounds__(256) qp_kernel(const float* __restrict__ Wq, const float* __restrict__ Wk,
                                                 const float* __restrict__ Wv, const float* __restrict__ Wg,
                                                 const float* __restrict__ bg, const float* __restrict__ an,
                                                 float* __restrict__ qt, float* __restrict__ kt,
                                                 float* __restrict__ vt, float* __restrict__ gt,
                                                 const float* __restrict__ z, const float* __restrict__ wz2,
                                                 const float* __restrict__ sh, const float* __restrict__ bh,
                                                 float* __restrict__ bias) {
    const int b = blockIdx.x;
    if (b < 768) {
        const int lane = threadIdx.x & 63;
        const int w = __builtin_amdgcn_readfirstlane(threadIdx.x >> 6);
        const int wid = b * 4 + w;            // 0..3071
        const int strip = wid >> 3;           // 0..383
        const int mb = wid & 7;
        const int n0 = strip * 4;
        const int sel = n0 / HD;              // 0:q 1:k 2:v 3:g
        const int col = n0 % HD;
        const float* Wm = (sel == 0) ? Wq : (sel == 1) ? Wk : (sel == 2) ? Wv : Wg;
        const int m = mb * 64 + lane;
        const float* arow = an + m * CS;
        float acc[4];
        #pragma unroll
        for (int j = 0; j < 4; ++j) acc[j] = 0.f;
        for (int kb = 0; kb < CS; kb += 32) {
            float4 av[8];
            #pragma unroll
            for (int i = 0; i < 8; ++i) av[i] = ((const float4*)(arow + kb))[i]; // full 128B line
            #pragma unroll
            for (int i = 0; i < 8; ++i) {
                const float* wr = Wm + (kb + i * 4) * HD + col; // wave-uniform -> s_load
                #pragma unroll
                for (int j = 0; j < 4; ++j) {
                    acc[j] += av[i].x * wr[j];
                    acc[j] += av[i].y * wr[HD + j];
                    acc[j] += av[i].z * wr[2 * HD + j];
                    acc[j] += av[i].w * wr[3 * HD + j];
                }
            }
        }
        float* dst = (sel == 0) ? qt : (sel == 1) ? kt : (sel == 2) ? vt : gt;
        if (sel == 3) {
            #pragma unroll
            for (int j = 0; j < 4; ++j) acc[j] = 1.f / (1.f + __expf(-(acc[j] + bg[col + j])));
        } else if (sel == 0) {
            #pragma unroll
            for (int j = 0; j < 4; ++j) acc[j] *= 0.20412414523193153f; // 1/sqrt(24)
        }
        #pragma unroll
        for (int j = 0; j < 4; ++j) {
            int c = col + j;
            int h = c / DH, d = c % DH;
            dst[(h * N + m) * DH + d] = acc[j];
        }
    } else {
        // fused z-LN + z_n@Wz -> pair bias [H][N][N]; one (i,j) row of z per lane
        const int row = (b - 768) * 256 + threadIdx.x; // 0..262143
        const float* zr = z + (size_t)row * CZ;
        float dots[NH];
        #pragma unroll
        for (int h = 0; h < NH; ++h) dots[h] = 0.f;
        float s1 = 0.f, s2 = 0.f;
        #pragma unroll
        for (int cb = 0; cb < CZ; cb += 32) {
            float4 zv[8];
            #pragma unroll
            for (int i = 0; i < 8; ++i) zv[i] = ((const float4*)(zr + cb))[i]; // 128B line/lane
            #pragma unroll
            for (int i = 0; i < 8; ++i) {
                s1 += zv[i].x + zv[i].y + zv[i].z + zv[i].w;
                s2 += zv[i].x * zv[i].x + zv[i].y * zv[i].y + zv[i].z * zv[i].z + zv[i].w * zv[i].w;
            }
            #pragma unroll
            for (int h = 0; h < NH; ++h) {
                const float* wrow = wz2 + h * CZ + cb; // wave-uniform, read-only -> s_load
                float d = dots[h];
                #pragma unroll
                for (int i = 0; i < 8; ++i) {
                    d += zv[i].x * wrow[i * 4 + 0];
                    d += zv[i].y * wrow[i * 4 + 1];
                    d += zv[i].z * wrow[i * 4 + 2];
                    d += zv[i].w * wrow[i * 4 + 3];
                }
                dots[h] = d;
            }
        }
        float mu = s1 * (1.f / CZ);
        float var = s2 * (1.f / CZ) - mu * mu;
        float r = rsqrtf(var + EPS);
        #pragma unroll
        for (int h = 0; h < NH; ++h)
            bias[h * NN + row] = r * (dots[h] - mu * sh[h]) + bh[h];
    }
}

// ---------------- attention: 2 q per wave, 32 lanes per q over k. 4096 waves ----------------
__global__ void __launch_bounds__(256) attn_kernel(const float* __restrict__ qt, const float* __restrict__ kt,
                                                   const float* __restrict__ vt, const float* __restrict__ gt,
                                                   const float* __restrict__ bias, float* __restrict__ og) {
    const int lane = threadIdx.x & 63;
    const int w = __builtin_amdgcn_readfirstlane(threadIdx.x >> 6);
    const int qhalf = lane >> 5;     // 0/1
    const int klane = lane & 31;
    const int h = blockIdx.y;
    const int q = blockIdx.x * 8 + w * 2 + qhalf;
    const float* qT = qt + h * N * DH;
    const float* kT = kt + h * N * DH;
    const float* vT = vt + h * N * DH;

    float qv[DH];
    #pragma unroll
    for (int d6 = 0; d6 < 6; ++d6) {
        float4 t4 = ((const float4*)(qT + q * DH))[d6];
        qv[d6 * 4 + 0] = t4.x; qv[d6 * 4 + 1] = t4.y; qv[d6 * 4 + 2] = t4.z; qv[d6 * 4 + 3] = t4.w;
    }
    float sc[16];
    #pragma unroll
    for (int t = 0; t < 16; ++t) {
        const int kk = t * 32 + klane;
        const float4* kr = (const float4*)(kT + kk * DH);
        float4 k0 = kr[0], k1 = kr[1], k2 = kr[2], k3 = kr[3], k4 = kr[4], k5 = kr[5];
        float s = qv[0]*k0.x + qv[1]*k0.y + qv[2]*k0.z + qv[3]*k0.w
                + qv[4]*k1.x + qv[5]*k1.y + qv[6]*k1.z + qv[7]*k1.w
                + qv[8]*k2.x + qv[9]*k2.y + qv[10]*k2.z + qv[11]*k2.w
                + qv[12]*k3.x + qv[13]*k3.y + qv[14]*k3.z + qv[15]*k3.w
                + qv[16]*k4.x + qv[17]*k4.y + qv[18]*k4.z + qv[19]*k4.w
                + qv[20]*k5.x + qv[21]*k5.y + qv[22]*k5.z + qv[23]*k5.w;
        sc[t] = s + bias[h * NN + q * N + kk];
    }
    float mx = sc[0];
    #pragma unroll
    for (int t = 1; t < 16; ++t) mx = fmaxf(mx, sc[t]);
    #pragma unroll
    for (int m = 1; m < 32; m <<= 1) mx = fmaxf(mx, __shfl_xor(mx, m, 64));
    float sum = 0.f;
    #pragma unroll
    for (int t = 0; t < 16; ++t) { sc[t] = __expf(sc[t] - mx); sum += sc[t]; }
    #pragma unroll
    for (int m = 1; m < 32; m <<= 1) sum += __shfl_xor(sum, m, 64);
    float inv = 1.f / sum;
    #pragma unroll
    for (int t = 0; t < 16; ++t) sc[t] *= inv;
    float acc[DH];
    #pragma unroll
    for (int d = 0; d < DH; ++d) acc[d] = 0.f;
    #pragma unroll
    for (int t = 0; t < 16; ++t) {
        const int kk = t * 32 + klane;
        const float4* vr = (const float4*)(vT + kk * DH);
        float4 v0 = vr[0], v1 = vr[1], v2 = vr[2], v3 = vr[3], v4 = vr[4], v5 = vr[5];
        float p = sc[t];
        acc[0] += p*v0.x;  acc[1] += p*v0.y;  acc[2] += p*v0.z;  acc[3] += p*v0.w;
        acc[4] += p*v1.x;  acc[5] += p*v1.y;  acc[6] += p*v1.z;  acc[7] += p*v1.w;
        acc[8] += p*v2.x;  acc[9] += p*v2.y;  acc[10] += p*v2.z; acc[11] += p*v2.w;
        acc[12] += p*v3.x; acc[13] += p*v3.y; acc[14] += p*v3.z; acc[15] += p*v3.w;
        acc[16] += p*v4.x; acc[17] += p*v4.y; acc[18] += p*v4.z; acc[19] += p*v4.w;
        acc[20] += p*v5.x; acc[21] += p*v5.y; acc[22] += p*v5.z; acc[23] += p*v5.w;
    }
    #pragma unroll
    for (int m = 1; m < 32; m <<= 1) {
        #pragma unroll
        for (int d = 0; d < DH; ++d) acc[d] += __shfl_xor(acc[d], m, 64);
    }
    float o = 0.f;
    #pragma unroll
    for (int d = 0; d < DH; ++d) o = (klane == d) ? acc[d] : o;
    if (klane < DH) {
        float g = gt[h * N * DH + q * DH + klane];
        og[q * HD + h * DH + klane] = o * g;
    }
}

// ---------------- out = og @ Wo + bo (2 cols/thread, 1536 waves — 2x prev occupancy) ----------------
__global__ void __launch_bounds__(256) out_gemm_kernel(const float* __restrict__ Wo, const float* __restrict__ bo,
                                                       const float* __restrict__ og, float* __restrict__ out) {
    const int lane = threadIdx.x & 63;
    const int w = __builtin_amdgcn_readfirstlane(threadIdx.x >> 6);
    const int wid = blockIdx.x * 4 + w;   // 0..1535
    const int strip = wid >> 3;           // 0..191
    const int mb = wid & 7;
    const int c0 = strip * 2;
    const int m = mb * 64 + lane;
    const float* orow = og + m * HD;
    float acc[2];
    acc[0] = 0.f; acc[1] = 0.f;
    for (int kb = 0; kb < HD; kb += 32) {
        float4 av[8];
        #pragma unroll
        for (int i = 0; i < 8; ++i) av[i] = ((const float4*)(orow + kb))[i];
        #pragma unroll
        for (int i = 0; i < 8; ++i) {
            const float* wr = Wo + (kb + i * 4) * CS + c0; // uniform -> s_load
            #pragma unroll
            for (int j = 0; j < 2; ++j) {
                acc[j] += av[i].x * wr[j];
                acc[j] += av[i].y * wr[CS + j];
                acc[j] += av[i].z * wr[2 * CS + j];
                acc[j] += av[i].w * wr[3 * CS + j];
            }
        }
    }
    #pragma unroll
    for (int j = 0; j < 2; ++j) out[m * CS + c0 + j] = acc[j] + bo[c0 + j];
}

extern "C" void kernel_launch(void* const* d_in, const int* in_sizes, int n_in,
                              void* d_out, int out_size, void* d_ws, size_t ws_size,
                              hipStream_t stream) {
    const float* a    = (const float*)d_in[0];
    const float* z    = (const float*)d_in[1];
    const float* g_a  = (const float*)d_in[2];
    const float* b_a  = (const float*)d_in[3];
    const float* g_z  = (const float*)d_in[4];
    const float* b_z  = (const float*)d_in[5];
    const float* Wz   = (const float*)d_in[6];
    const float* bz   = (const float*)d_in[7];
    const float* Wq   = (const float*)d_in[8];
    const float* Wk   = (const float*)d_in[9];
    const float* Wv   = (const float*)d_in[10];
    const float* Wg   = (const float*)d_in[11];
    const float* bg   = (const float*)d_in[12];
    const float* Wo   = (const float*)d_in[13];
    const float* bo   = (const float*)d_in[14];
    float* ws  = (float*)d_ws;
    float* out = (float*)d_out;

    float* an   = ws + OFF_AN;
    float* qt   = ws + OFF_QT;
    float* kt   = ws + OFF_KT;
    float* vt   = ws + OFF_VT;
    float* gt   = ws + OFF_GT;
    float* ogp  = ws + OFF_OG;
    float* wz2  = ws + OFF_WZ2;
    float* shp  = ws + OFF_SH;
    float* bhp  = ws + OFF_BH;
    float* bias = ws + OFF_BIAS;

    hipLaunchKernelGGL(ln_prep_kernel, dim3(257),    dim3(256), 0, stream,
                       a, g_a, b_a, an, g_z, b_z, Wz, bz, wz2, shp, bhp);
    hipLaunchKernelGGL(qp_kernel,      dim3(1792),   dim3(256), 0, stream,
                       Wq, Wk, Wv, Wg, bg, an, qt, kt, vt, gt, z, wz2, shp, bhp, bias);
    hipLaunchKernelGGL(attn_kernel,    dim3(64, 16), dim3(256), 0, stream,
                       qt, kt, vt, gt, bias, ogp);
    hipLaunchKernelGGL(out_gemm_kernel, dim3(384),   dim3(256), 0, stream,
                       Wo, bo, ogp, out);
}

// Round 2
// 356.433 us; speedup vs baseline: 1.0178x; 1.0178x over previous
//
#include <hip/hip_runtime.h>
#include <math.h>

#define N 512
#define CS 384
#define CZ 128
#define NH 16
#define DH 24
#define HD 384
#define NN (N*N)
#define EPS 1e-5f

// ws layout (float offsets)
#define OFF_AN   0          // a_n [N][CS]
#define OFF_QT   196608     // qT [H][N][D] (pre-scaled by 1/sqrt(24))
#define OFF_KT   393216     // kT [H][N][D]
#define OFF_VT   589824     // vT [H][N][D]
#define OFF_GT   786432     // gT [H][N][D] (sigmoid applied)
#define OFF_OG   983040     // o*g [N][HD]
#define OFF_WZ2  1179648    // g_z*Wz transposed [H][CZ]
#define OFF_SH   1181696    // [H]
#define OFF_BH   1181712    // [H]
#define OFF_BIAS 1181728    // pair bias [H][N][N]

// ---------------- fused: prep (block 256) + LayerNorm of a (blocks 0..255, 2 rows each) ----------------
__global__ void __launch_bounds__(256) ln_prep_kernel(const float* __restrict__ a, const float* __restrict__ g_a,
                                                      const float* __restrict__ b_a, float* __restrict__ an_out,
                                                      const float* __restrict__ g_z, const float* __restrict__ lnb_z,
                                                      const float* __restrict__ Wz, const float* __restrict__ bz,
                                                      float* __restrict__ wz2, float* __restrict__ sh,
                                                      float* __restrict__ bh) {
    __shared__ float ls[NH][17], lb[NH][17];   // prep block
    __shared__ float l1[4], l2[4];             // ln blocks
    const int t = threadIdx.x;
    if (blockIdx.x == 256) {
        // prep: Wz2[h][c] = g_z[c]*Wz[c][h]; Sh, Bh
        for (int i = t; i < NH * CZ; i += 256) {
            int h = i >> 7, c = i & (CZ - 1);
            wz2[h * CZ + c] = g_z[c] * Wz[c * NH + h];
        }
        int h = t >> 4, seg = t & 15;
        float s = 0.f, b = 0.f;
        #pragma unroll
        for (int i = 0; i < 8; ++i) {
            int c = seg * 8 + i;
            float w = Wz[c * NH + h];
            s += g_z[c] * w;
            b += lnb_z[c] * w;
        }
        ls[h][seg] = s; lb[h][seg] = b;
        __syncthreads();
        if (t < NH) {
            float ss = 0.f, bb = 0.f;
            #pragma unroll
            for (int i = 0; i < 16; ++i) { ss += ls[t][i]; bb += lb[t][i]; }
            sh[t] = ss;
            bh[t] = bb + bz[t];
        }
        return;
    }
    // LayerNorm: 2 rows per block (threads 0..127 -> row0, 128..255 -> row1)
    const int half = t >> 7;
    const int tr = t & 127;
    const int r = blockIdx.x * 2 + half;
    const float* row = a + r * CS;
    float x0 = row[tr], x1 = row[tr + 128], x2 = row[tr + 256];
    float s1 = x0 + x1 + x2;
    float s2 = x0 * x0 + x1 * x1 + x2 * x2;
    #pragma unroll
    for (int m = 1; m < 64; m <<= 1) {
        s1 += __shfl_xor(s1, m, 64);
        s2 += __shfl_xor(s2, m, 64);
    }
    if ((t & 63) == 0) { l1[t >> 6] = s1; l2[t >> 6] = s2; }
    __syncthreads();
    s1 = l1[half * 2] + l1[half * 2 + 1];
    s2 = l2[half * 2] + l2[half * 2 + 1];
    float mu = s1 * (1.f / CS);
    float var = s2 * (1.f / CS) - mu * mu;
    float rs = rsqrtf(var + EPS);
    float* an = an_out + r * CS;
    an[tr]       = (x0 - mu) * rs * g_a[tr]       + b_a[tr];
    an[tr + 128] = (x1 - mu) * rs * g_a[tr + 128] + b_a[tr + 128];
    an[tr + 256] = (x2 - mu) * rs * g_a[tr + 256] + b_a[tr + 256];
}

// ---------------- q,k,v,g projections (scalar-B GEMM, 8 cols/thread) — round-0 proven ----------------
// grid (48, 8), block 256. wave -> 8-col strip of [Wq|Wk|Wv|Wg]; lane -> row. 1536 waves.
__global__ void __launch_bounds__(256) qkvg_kernel(const float* __restrict__ Wq, const float* __restrict__ Wk,
                                                   const float* __restrict__ Wv, const float* __restrict__ Wg,
                                                   const float* __restrict__ bg, const float* __restrict__ an,
                                                   float* __restrict__ qt, float* __restrict__ kt,
                                                   float* __restrict__ vt, float* __restrict__ gt) {
    const int lane = threadIdx.x & 63;
    const int w = __builtin_amdgcn_readfirstlane(threadIdx.x >> 6);
    const int strip = blockIdx.x * 4 + w;     // 0..191
    const int n0 = strip * 8;
    const int sel = n0 / HD;                  // 0:q 1:k 2:v 3:g
    const int col = n0 % HD;
    const float* Wm = (sel == 0) ? Wq : (sel == 1) ? Wk : (sel == 2) ? Wv : Wg;
    const int m = blockIdx.y * 64 + lane;
    const float* arow = an + m * CS;
    float acc[8];
    #pragma unroll
    for (int j = 0; j < 8; ++j) acc[j] = 0.f;
    for (int kb = 0; kb < CS; kb += 32) {
        float4 av[8];
        #pragma unroll
        for (int i = 0; i < 8; ++i) av[i] = ((const float4*)(arow + kb))[i]; // full 128B line
        #pragma unroll
        for (int i = 0; i < 8; ++i) {
            const float* wr = Wm + (kb + i * 4) * HD + col; // wave-uniform -> s_load
            #pragma unroll
            for (int j = 0; j < 8; ++j) {
                acc[j] += av[i].x * wr[j];
                acc[j] += av[i].y * wr[HD + j];
                acc[j] += av[i].z * wr[2 * HD + j];
                acc[j] += av[i].w * wr[3 * HD + j];
            }
        }
    }
    float* dst = (sel == 0) ? qt : (sel == 1) ? kt : (sel == 2) ? vt : gt;
    if (sel == 3) {
        #pragma unroll
        for (int j = 0; j < 8; ++j) acc[j] = 1.f / (1.f + __expf(-(acc[j] + bg[col + j])));
    } else if (sel == 0) {
        #pragma unroll
        for (int j = 0; j < 8; ++j) acc[j] *= 0.20412414523193153f; // 1/sqrt(24)
    }
    #pragma unroll
    for (int j = 0; j < 8; ++j) {
        int c = col + j;
        int h = c / DH, d = c % DH;
        dst[(h * N + m) * DH + d] = acc[j];
    }
}

// ---------------- fused z-LN + z_n@Wz -> pair bias [H][N][N] — COALESCED rewrite ----------------
// 16 lanes per z-row: lane cl reads z[row][cl*8 .. cl*8+8) (32B). A wave covers 4 rows = 2KB contiguous.
// Per-lane partial dots for all 16 heads; 4-step shfl_xor butterfly within 16-lane groups;
// lane cl writes head cl. 2048 blocks x 4 waves = 8192 waves (full occupancy for BW).
__global__ void __launch_bounds__(256) pairbias_kernel(const float* __restrict__ z,
                                                       const float* __restrict__ wz2,
                                                       const float* __restrict__ sh,
                                                       const float* __restrict__ bh,
                                                       float* __restrict__ bias) {
    const int lane = threadIdx.x & 63;
    const int w = threadIdx.x >> 6;
    const int r4 = lane >> 4;      // row within 4-row group
    const int cl = lane & 15;      // column-lane (covers 8 floats)
    const int wave_row0 = blockIdx.x * 128 + w * 32;   // 32 rows per wave
    const float shc = sh[cl];
    const float bhc = bh[cl];
    for (int g = 0; g < 8; ++g) {
        const int row = wave_row0 + g * 4 + r4;
        const float* zr = z + (size_t)row * CZ + cl * 8;
        float4 z0 = ((const float4*)zr)[0];
        float4 z1 = ((const float4*)zr)[1];
        float s1 = z0.x + z0.y + z0.z + z0.w + z1.x + z1.y + z1.z + z1.w;
        float s2 = z0.x*z0.x + z0.y*z0.y + z0.z*z0.z + z0.w*z0.w
                 + z1.x*z1.x + z1.y*z1.y + z1.z*z1.z + z1.w*z1.w;
        float dots[NH];
        #pragma unroll
        for (int h = 0; h < NH; ++h) {
            const float4* wp = (const float4*)(wz2 + h * CZ + cl * 8); // L1-resident (8KB)
            float4 w0 = wp[0], w1 = wp[1];
            dots[h] = z0.x*w0.x + z0.y*w0.y + z0.z*w0.z + z0.w*w0.w
                    + z1.x*w1.x + z1.y*w1.y + z1.z*w1.z + z1.w*w1.w;
        }
        // butterfly reduce over the 16 column-lanes (xor masks 1,2,4,8 stay within the group)
        #pragma unroll
        for (int m = 1; m < 16; m <<= 1) {
            s1 += __shfl_xor(s1, m, 64);
            s2 += __shfl_xor(s2, m, 64);
            #pragma unroll
            for (int h = 0; h < NH; ++h) dots[h] += __shfl_xor(dots[h], m, 64);
        }
        float mu = s1 * (1.f / CZ);
        float var = s2 * (1.f / CZ) - mu * mu;
        float rr = rsqrtf(var + EPS);
        // select dots[cl] without runtime register indexing (rule #20)
        float d = dots[0];
        #pragma unroll
        for (int h = 1; h < NH; ++h) d = (cl == h) ? dots[h] : d;
        bias[cl * NN + row] = rr * (d - mu * shc) + bhc;
    }
}

// ---------------- attention: 2 q per wave, 32 lanes per q over k. 4096 waves ----------------
__global__ void __launch_bounds__(256) attn_kernel(const float* __restrict__ qt, const float* __restrict__ kt,
                                                   const float* __restrict__ vt, const float* __restrict__ gt,
                                                   const float* __restrict__ bias, float* __restrict__ og) {
    const int lane = threadIdx.x & 63;
    const int w = __builtin_amdgcn_readfirstlane(threadIdx.x >> 6);
    const int qhalf = lane >> 5;     // 0/1
    const int klane = lane & 31;
    const int h = blockIdx.y;
    const int q = blockIdx.x * 8 + w * 2 + qhalf;
    const float* qT = qt + h * N * DH;
    const float* kT = kt + h * N * DH;
    const float* vT = vt + h * N * DH;

    float qv[DH];
    #pragma unroll
    for (int d6 = 0; d6 < 6; ++d6) {
        float4 t4 = ((const float4*)(qT + q * DH))[d6];
        qv[d6 * 4 + 0] = t4.x; qv[d6 * 4 + 1] = t4.y; qv[d6 * 4 + 2] = t4.z; qv[d6 * 4 + 3] = t4.w;
    }
    float sc[16];
    #pragma unroll
    for (int t = 0; t < 16; ++t) {
        const int kk = t * 32 + klane;
        const float4* kr = (const float4*)(kT + kk * DH);
        float4 k0 = kr[0], k1 = kr[1], k2 = kr[2], k3 = kr[3], k4 = kr[4], k5 = kr[5];
        float s = qv[0]*k0.x + qv[1]*k0.y + qv[2]*k0.z + qv[3]*k0.w
                + qv[4]*k1.x + qv[5]*k1.y + qv[6]*k1.z + qv[7]*k1.w
                + qv[8]*k2.x + qv[9]*k2.y + qv[10]*k2.z + qv[11]*k2.w
                + qv[12]*k3.x + qv[13]*k3.y + qv[14]*k3.z + qv[15]*k3.w
                + qv[16]*k4.x + qv[17]*k4.y + qv[18]*k4.z + qv[19]*k4.w
                + qv[20]*k5.x + qv[21]*k5.y + qv[22]*k5.z + qv[23]*k5.w;
        sc[t] = s + bias[h * NN + q * N + kk];
    }
    float mx = sc[0];
    #pragma unroll
    for (int t = 1; t < 16; ++t) mx = fmaxf(mx, sc[t]);
    #pragma unroll
    for (int m = 1; m < 32; m <<= 1) mx = fmaxf(mx, __shfl_xor(mx, m, 64));
    float sum = 0.f;
    #pragma unroll
    for (int t = 0; t < 16; ++t) { sc[t] = __expf(sc[t] - mx); sum += sc[t]; }
    #pragma unroll
    for (int m = 1; m < 32; m <<= 1) sum += __shfl_xor(sum, m, 64);
    float inv = 1.f / sum;
    #pragma unroll
    for (int t = 0; t < 16; ++t) sc[t] *= inv;
    float acc[DH];
    #pragma unroll
    for (int d = 0; d < DH; ++d) acc[d] = 0.f;
    #pragma unroll
    for (int t = 0; t < 16; ++t) {
        const int kk = t * 32 + klane;
        const float4* vr = (const float4*)(vT + kk * DH);
        float4 v0 = vr[0], v1 = vr[1], v2 = vr[2], v3 = vr[3], v4 = vr[4], v5 = vr[5];
        float p = sc[t];
        acc[0] += p*v0.x;  acc[1] += p*v0.y;  acc[2] += p*v0.z;  acc[3] += p*v0.w;
        acc[4] += p*v1.x;  acc[5] += p*v1.y;  acc[6] += p*v1.z;  acc[7] += p*v1.w;
        acc[8] += p*v2.x;  acc[9] += p*v2.y;  acc[10] += p*v2.z; acc[11] += p*v2.w;
        acc[12] += p*v3.x; acc[13] += p*v3.y; acc[14] += p*v3.z; acc[15] += p*v3.w;
        acc[16] += p*v4.x; acc[17] += p*v4.y; acc[18] += p*v4.z; acc[19] += p*v4.w;
        acc[20] += p*v5.x; acc[21] += p*v5.y; acc[22] += p*v5.z; acc[23] += p*v5.w;
    }
    #pragma unroll
    for (int m = 1; m < 32; m <<= 1) {
        #pragma unroll
        for (int d = 0; d < DH; ++d) acc[d] += __shfl_xor(acc[d], m, 64);
    }
    float o = 0.f;
    #pragma unroll
    for (int d = 0; d < DH; ++d) o = (klane == d) ? acc[d] : o;
    if (klane < DH) {
        float g = gt[h * N * DH + q * DH + klane];
        og[q * HD + h * DH + klane] = o * g;
    }
}

// ---------------- out = og @ Wo + bo (4 cols/thread, 768 waves) — round-0 proven ----------------
__global__ void __launch_bounds__(256) out_gemm_kernel(const float* __restrict__ Wo, const float* __restrict__ bo,
                                                       const float* __restrict__ og, float* __restrict__ out) {
    const int lane = threadIdx.x & 63;
    const int w = __builtin_amdgcn_readfirstlane(threadIdx.x >> 6);
    const int strip = blockIdx.x * 4 + w;  // 0..95
    const int c0 = strip * 4;
    const int m = blockIdx.y * 64 + lane;
    const float* orow = og + m * HD;
    float acc[4];
    #pragma unroll
    for (int j = 0; j < 4; ++j) acc[j] = 0.f;
    for (int kb = 0; kb < HD; kb += 32) {
        float4 av[8];
        #pragma unroll
        for (int i = 0; i < 8; ++i) av[i] = ((const float4*)(orow + kb))[i];
        #pragma unroll
        for (int i = 0; i < 8; ++i) {
            const float* wr = Wo + (kb + i * 4) * CS + c0; // uniform -> s_load
            #pragma unroll
            for (int j = 0; j < 4; ++j) {
                acc[j] += av[i].x * wr[j];
                acc[j] += av[i].y * wr[CS + j];
                acc[j] += av[i].z * wr[2 * CS + j];
                acc[j] += av[i].w * wr[3 * CS + j];
            }
        }
    }
    #pragma unroll
    for (int j = 0; j < 4; ++j) out[m * CS + c0 + j] = acc[j] + bo[c0 + j];
}

extern "C" void kernel_launch(void* const* d_in, const int* in_sizes, int n_in,
                              void* d_out, int out_size, void* d_ws, size_t ws_size,
                              hipStream_t stream) {
    const float* a    = (const float*)d_in[0];
    const float* z    = (const float*)d_in[1];
    const float* g_a  = (const float*)d_in[2];
    const float* b_a  = (const float*)d_in[3];
    const float* g_z  = (const float*)d_in[4];
    const float* b_z  = (const float*)d_in[5];
    const float* Wz   = (const float*)d_in[6];
    const float* bz   = (const float*)d_in[7];
    const float* Wq   = (const float*)d_in[8];
    const float* Wk   = (const float*)d_in[9];
    const float* Wv   = (const float*)d_in[10];
    const float* Wg   = (const float*)d_in[11];
    const float* bg   = (const float*)d_in[12];
    const float* Wo   = (const float*)d_in[13];
    const float* bo   = (const float*)d_in[14];
    float* ws  = (float*)d_ws;
    float* out = (float*)d_out;

    float* an   = ws + OFF_AN;
    float* qt   = ws + OFF_QT;
    float* kt   = ws + OFF_KT;
    float* vt   = ws + OFF_VT;
    float* gt   = ws + OFF_GT;
    float* ogp  = ws + OFF_OG;
    float* wz2  = ws + OFF_WZ2;
    float* shp  = ws + OFF_SH;
    float* bhp  = ws + OFF_BH;
    float* bias = ws + OFF_BIAS;

    hipLaunchKernelGGL(ln_prep_kernel, dim3(257),    dim3(256), 0, stream,
                       a, g_a, b_a, an, g_z, b_z, Wz, bz, wz2, shp, bhp);
    hipLaunchKernelGGL(qkvg_kernel,    dim3(48, 8),  dim3(256), 0, stream,
                       Wq, Wk, Wv, Wg, bg, an, qt, kt, vt, gt);
    hipLaunchKernelGGL(pairbias_kernel, dim3(2048),  dim3(256), 0, stream,
                       z, wz2, shp, bhp, bias);
    hipLaunchKernelGGL(attn_kernel,    dim3(64, 16), dim3(256), 0, stream,
                       qt, kt, vt, gt, bias, ogp);
    hipLaunchKernelGGL(out_gemm_kernel, dim3(24, 8), dim3(256), 0, stream,
                       Wo, bo, ogp, out);
}

// Round 3
// 349.496 us; speedup vs baseline: 1.0380x; 1.0198x over previous
//
#include <hip/hip_runtime.h>
#include <math.h>

#define N 512
#define CS 384
#define CZ 128
#define NH 16
#define DH 24
#define HD 384
#define NN (N*N)
#define EPS 1e-5f

// ws layout (float offsets)
#define OFF_AN   0          // a_n [N][CS]
#define OFF_QT   196608     // qT [H][N][D] (pre-scaled by 1/sqrt(24))
#define OFF_KT   393216     // kT [H][N][D]
#define OFF_VT   589824     // vT [H][N][D]
#define OFF_GT   786432     // gT [H][N][D] (sigmoid applied)
#define OFF_OG   983040     // o*g [N][HD]
#define OFF_WZ2  1179648    // g_z*Wz transposed [H][CZ]
#define OFF_SH   1181696    // [H]
#define OFF_BH   1181712    // [H]
#define OFF_BIAS 1181728    // pair bias [H][N][N]

// ---------------- fused: prep (block 256) + LayerNorm of a (blocks 0..255, 2 rows each) ----------------
__global__ void __launch_bounds__(256) ln_prep_kernel(const float* __restrict__ a, const float* __restrict__ g_a,
                                                      const float* __restrict__ b_a, float* __restrict__ an_out,
                                                      const float* __restrict__ g_z, const float* __restrict__ lnb_z,
                                                      const float* __restrict__ Wz, const float* __restrict__ bz,
                                                      float* __restrict__ wz2, float* __restrict__ sh,
                                                      float* __restrict__ bh) {
    __shared__ float ls[NH][17], lb[NH][17];   // prep block
    __shared__ float l1[4], l2[4];             // ln blocks
    const int t = threadIdx.x;
    if (blockIdx.x == 256) {
        // prep: Wz2[h][c] = g_z[c]*Wz[c][h]; Sh, Bh
        for (int i = t; i < NH * CZ; i += 256) {
            int h = i >> 7, c = i & (CZ - 1);
            wz2[h * CZ + c] = g_z[c] * Wz[c * NH + h];
        }
        int h = t >> 4, seg = t & 15;
        float s = 0.f, b = 0.f;
        #pragma unroll
        for (int i = 0; i < 8; ++i) {
            int c = seg * 8 + i;
            float w = Wz[c * NH + h];
            s += g_z[c] * w;
            b += lnb_z[c] * w;
        }
        ls[h][seg] = s; lb[h][seg] = b;
        __syncthreads();
        if (t < NH) {
            float ss = 0.f, bb = 0.f;
            #pragma unroll
            for (int i = 0; i < 16; ++i) { ss += ls[t][i]; bb += lb[t][i]; }
            sh[t] = ss;
            bh[t] = bb + bz[t];
        }
        return;
    }
    // LayerNorm: 2 rows per block (threads 0..127 -> row0, 128..255 -> row1)
    const int half = t >> 7;
    const int tr = t & 127;
    const int r = blockIdx.x * 2 + half;
    const float* row = a + r * CS;
    float x0 = row[tr], x1 = row[tr + 128], x2 = row[tr + 256];
    float s1 = x0 + x1 + x2;
    float s2 = x0 * x0 + x1 * x1 + x2 * x2;
    #pragma unroll
    for (int m = 1; m < 64; m <<= 1) {
        s1 += __shfl_xor(s1, m, 64);
        s2 += __shfl_xor(s2, m, 64);
    }
    if ((t & 63) == 0) { l1[t >> 6] = s1; l2[t >> 6] = s2; }
    __syncthreads();
    s1 = l1[half * 2] + l1[half * 2 + 1];
    s2 = l2[half * 2] + l2[half * 2 + 1];
    float mu = s1 * (1.f / CS);
    float var = s2 * (1.f / CS) - mu * mu;
    float rs = rsqrtf(var + EPS);
    float* an = an_out + r * CS;
    an[tr]       = (x0 - mu) * rs * g_a[tr]       + b_a[tr];
    an[tr + 128] = (x1 - mu) * rs * g_a[tr + 128] + b_a[tr + 128];
    an[tr + 256] = (x2 - mu) * rs * g_a[tr + 256] + b_a[tr + 256];
}

// ---------------- q,k,v,g projections (scalar-B GEMM, 8 cols/thread) — round-0 proven ----------------
// grid (48, 8), block 256. wave -> 8-col strip of [Wq|Wk|Wv|Wg]; lane -> row. 1536 waves.
__global__ void __launch_bounds__(256) qkvg_kernel(const float* __restrict__ Wq, const float* __restrict__ Wk,
                                                   const float* __restrict__ Wv, const float* __restrict__ Wg,
                                                   const float* __restrict__ bg, const float* __restrict__ an,
                                                   float* __restrict__ qt, float* __restrict__ kt,
                                                   float* __restrict__ vt, float* __restrict__ gt) {
    const int lane = threadIdx.x & 63;
    const int w = __builtin_amdgcn_readfirstlane(threadIdx.x >> 6);
    const int strip = blockIdx.x * 4 + w;     // 0..191
    const int n0 = strip * 8;
    const int sel = n0 / HD;                  // 0:q 1:k 2:v 3:g
    const int col = n0 % HD;
    const float* Wm = (sel == 0) ? Wq : (sel == 1) ? Wk : (sel == 2) ? Wv : Wg;
    const int m = blockIdx.y * 64 + lane;
    const float* arow = an + m * CS;
    float acc[8];
    #pragma unroll
    for (int j = 0; j < 8; ++j) acc[j] = 0.f;
    for (int kb = 0; kb < CS; kb += 32) {
        float4 av[8];
        #pragma unroll
        for (int i = 0; i < 8; ++i) av[i] = ((const float4*)(arow + kb))[i]; // full 128B line
        #pragma unroll
        for (int i = 0; i < 8; ++i) {
            const float* wr = Wm + (kb + i * 4) * HD + col; // wave-uniform -> s_load
            #pragma unroll
            for (int j = 0; j < 8; ++j) {
                acc[j] += av[i].x * wr[j];
                acc[j] += av[i].y * wr[HD + j];
                acc[j] += av[i].z * wr[2 * HD + j];
                acc[j] += av[i].w * wr[3 * HD + j];
            }
        }
    }
    float* dst = (sel == 0) ? qt : (sel == 1) ? kt : (sel == 2) ? vt : gt;
    if (sel == 3) {
        #pragma unroll
        for (int j = 0; j < 8; ++j) acc[j] = 1.f / (1.f + __expf(-(acc[j] + bg[col + j])));
    } else if (sel == 0) {
        #pragma unroll
        for (int j = 0; j < 8; ++j) acc[j] *= 0.20412414523193153f; // 1/sqrt(24)
    }
    #pragma unroll
    for (int j = 0; j < 8; ++j) {
        int c = col + j;
        int h = c / DH, d = c % DH;
        dst[(h * N + m) * DH + d] = acc[j];
    }
}

// ---------------- pair bias v3: LDS-staged, shuffle-free ----------------
// Block 256 threads <-> 128 z-rows. Stage rows into LDS with coalesced float4 loads,
// XOR-swizzle (slot = cc ^ (r&31)) so the row-wise compute reads are 2-way (free).
// Each row owned by 2 threads split by head-group (0-7 / 8-15): no shuffles; s1/s2
// recomputed per thread (cheap). Weights via wave-uniform s_loads. Writes: for fixed
// head, a wave stores 64 consecutive floats (256B contiguous).
__global__ void __launch_bounds__(256) pairbias_kernel(const float* __restrict__ z,
                                                       const float* __restrict__ wz2,
                                                       const float* __restrict__ sh,
                                                       const float* __restrict__ bh,
                                                       float* __restrict__ bias) {
    __shared__ float4 lz[128 * 32];   // 64 KB
    const int t = threadIdx.x;
    const int r_l = t & 127;                                   // local row
    const int hg = __builtin_amdgcn_readfirstlane(t >> 7);     // head group (wave-uniform)
    const int h0 = hg * 8;
    const int row0 = blockIdx.x * 128;

    // stage: 128 rows x 32 float4 = 4096 float4; 16 per thread, 4KB contiguous per instr
    const float4* zsrc = (const float4*)(z + (size_t)row0 * CZ);
    #pragma unroll
    for (int i = 0; i < 16; ++i) {
        const int g4 = i * 256 + t;            // 0..4095
        float4 v = zsrc[g4];
        const int r = g4 >> 5, cc = g4 & 31;
        lz[r * 32 + (cc ^ (r & 31))] = v;
    }
    __syncthreads();

    float s1 = 0.f, s2 = 0.f;
    float dots[8];
    #pragma unroll
    for (int j = 0; j < 8; ++j) dots[j] = 0.f;
    #pragma unroll 8
    for (int cc = 0; cc < 32; ++cc) {
        float4 v = lz[r_l * 32 + (cc ^ (r_l & 31))];
        s1 += v.x + v.y + v.z + v.w;
        s2 += v.x * v.x + v.y * v.y + v.z * v.z + v.w * v.w;
        #pragma unroll
        for (int j = 0; j < 8; ++j) {
            const float4 wv = ((const float4*)(wz2 + (h0 + j) * CZ))[cc]; // wave-uniform -> s_load
            dots[j] += v.x * wv.x + v.y * wv.y + v.z * wv.z + v.w * wv.w;
        }
    }
    const float mu = s1 * (1.f / CZ);
    const float var = s2 * (1.f / CZ) - mu * mu;
    const float rr = rsqrtf(var + EPS);
    const int row = row0 + r_l;
    #pragma unroll
    for (int j = 0; j < 8; ++j)
        bias[(h0 + j) * NN + row] = rr * (dots[j] - mu * sh[h0 + j]) + bh[h0 + j];
}

// ---------------- attention: 2 q per wave, 32 lanes per q over k. 4096 waves ----------------
__global__ void __launch_bounds__(256) attn_kernel(const float* __restrict__ qt, const float* __restrict__ kt,
                                                   const float* __restrict__ vt, const float* __restrict__ gt,
                                                   const float* __restrict__ bias, float* __restrict__ og) {
    const int lane = threadIdx.x & 63;
    const int w = __builtin_amdgcn_readfirstlane(threadIdx.x >> 6);
    const int qhalf = lane >> 5;     // 0/1
    const int klane = lane & 31;
    const int h = blockIdx.y;
    const int q = blockIdx.x * 8 + w * 2 + qhalf;
    const float* qT = qt + h * N * DH;
    const float* kT = kt + h * N * DH;
    const float* vT = vt + h * N * DH;

    float qv[DH];
    #pragma unroll
    for (int d6 = 0; d6 < 6; ++d6) {
        float4 t4 = ((const float4*)(qT + q * DH))[d6];
        qv[d6 * 4 + 0] = t4.x; qv[d6 * 4 + 1] = t4.y; qv[d6 * 4 + 2] = t4.z; qv[d6 * 4 + 3] = t4.w;
    }
    float sc[16];
    #pragma unroll
    for (int t = 0; t < 16; ++t) {
        const int kk = t * 32 + klane;
        const float4* kr = (const float4*)(kT + kk * DH);
        float4 k0 = kr[0], k1 = kr[1], k2 = kr[2], k3 = kr[3], k4 = kr[4], k5 = kr[5];
        float s = qv[0]*k0.x + qv[1]*k0.y + qv[2]*k0.z + qv[3]*k0.w
                + qv[4]*k1.x + qv[5]*k1.y + qv[6]*k1.z + qv[7]*k1.w
                + qv[8]*k2.x + qv[9]*k2.y + qv[10]*k2.z + qv[11]*k2.w
                + qv[12]*k3.x + qv[13]*k3.y + qv[14]*k3.z + qv[15]*k3.w
                + qv[16]*k4.x + qv[17]*k4.y + qv[18]*k4.z + qv[19]*k4.w
                + qv[20]*k5.x + qv[21]*k5.y + qv[22]*k5.z + qv[23]*k5.w;
        sc[t] = s + bias[h * NN + q * N + kk];
    }
    float mx = sc[0];
    #pragma unroll
    for (int t = 1; t < 16; ++t) mx = fmaxf(mx, sc[t]);
    #pragma unroll
    for (int m = 1; m < 32; m <<= 1) mx = fmaxf(mx, __shfl_xor(mx, m, 64));
    float sum = 0.f;
    #pragma unroll
    for (int t = 0; t < 16; ++t) { sc[t] = __expf(sc[t] - mx); sum += sc[t]; }
    #pragma unroll
    for (int m = 1; m < 32; m <<= 1) sum += __shfl_xor(sum, m, 64);
    float inv = 1.f / sum;
    #pragma unroll
    for (int t = 0; t < 16; ++t) sc[t] *= inv;
    float acc[DH];
    #pragma unroll
    for (int d = 0; d < DH; ++d) acc[d] = 0.f;
    #pragma unroll
    for (int t = 0; t < 16; ++t) {
        const int kk = t * 32 + klane;
        const float4* vr = (const float4*)(vT + kk * DH);
        float4 v0 = vr[0], v1 = vr[1], v2 = vr[2], v3 = vr[3], v4 = vr[4], v5 = vr[5];
        float p = sc[t];
        acc[0] += p*v0.x;  acc[1] += p*v0.y;  acc[2] += p*v0.z;  acc[3] += p*v0.w;
        acc[4] += p*v1.x;  acc[5] += p*v1.y;  acc[6] += p*v1.z;  acc[7] += p*v1.w;
        acc[8] += p*v2.x;  acc[9] += p*v2.y;  acc[10] += p*v2.z; acc[11] += p*v2.w;
        acc[12] += p*v3.x; acc[13] += p*v3.y; acc[14] += p*v3.z; acc[15] += p*v3.w;
        acc[16] += p*v4.x; acc[17] += p*v4.y; acc[18] += p*v4.z; acc[19] += p*v4.w;
        acc[20] += p*v5.x; acc[21] += p*v5.y; acc[22] += p*v5.z; acc[23] += p*v5.w;
    }
    #pragma unroll
    for (int m = 1; m < 32; m <<= 1) {
        #pragma unroll
        for (int d = 0; d < DH; ++d) acc[d] += __shfl_xor(acc[d], m, 64);
    }
    float o = 0.f;
    #pragma unroll
    for (int d = 0; d < DH; ++d) o = (klane == d) ? acc[d] : o;
    if (klane < DH) {
        float g = gt[h * N * DH + q * DH + klane];
        og[q * HD + h * DH + klane] = o * g;
    }
}

// ---------------- out = og @ Wo + bo (4 cols/thread, 768 waves) — round-0 proven ----------------
__global__ void __launch_bounds__(256) out_gemm_kernel(const float* __restrict__ Wo, const float* __restrict__ bo,
                                                       const float* __restrict__ og, float* __restrict__ out) {
    const int lane = threadIdx.x & 63;
    const int w = __builtin_amdgcn_readfirstlane(threadIdx.x >> 6);
    const int strip = blockIdx.x * 4 + w;  // 0..95
    const int c0 = strip * 4;
    const int m = blockIdx.y * 64 + lane;
    const float* orow = og + m * HD;
    float acc[4];
    #pragma unroll
    for (int j = 0; j < 4; ++j) acc[j] = 0.f;
    for (int kb = 0; kb < HD; kb += 32) {
        float4 av[8];
        #pragma unroll
        for (int i = 0; i < 8; ++i) av[i] = ((const float4*)(orow + kb))[i];
        #pragma unroll
        for (int i = 0; i < 8; ++i) {
            const float* wr = Wo + (kb + i * 4) * CS + c0; // uniform -> s_load
            #pragma unroll
            for (int j = 0; j < 4; ++j) {
                acc[j] += av[i].x * wr[j];
                acc[j] += av[i].y * wr[CS + j];
                acc[j] += av[i].z * wr[2 * CS + j];
                acc[j] += av[i].w * wr[3 * CS + j];
            }
        }
    }
    #pragma unroll
    for (int j = 0; j < 4; ++j) out[m * CS + c0 + j] = acc[j] + bo[c0 + j];
}

extern "C" void kernel_launch(void* const* d_in, const int* in_sizes, int n_in,
                              void* d_out, int out_size, void* d_ws, size_t ws_size,
                              hipStream_t stream) {
    const float* a    = (const float*)d_in[0];
    const float* z    = (const float*)d_in[1];
    const float* g_a  = (const float*)d_in[2];
    const float* b_a  = (const float*)d_in[3];
    const float* g_z  = (const float*)d_in[4];
    const float* b_z  = (const float*)d_in[5];
    const float* Wz   = (const float*)d_in[6];
    const float* bz   = (const float*)d_in[7];
    const float* Wq   = (const float*)d_in[8];
    const float* Wk   = (const float*)d_in[9];
    const float* Wv   = (const float*)d_in[10];
    const float* Wg   = (const float*)d_in[11];
    const float* bg   = (const float*)d_in[12];
    const float* Wo   = (const float*)d_in[13];
    const float* bo   = (const float*)d_in[14];
    float* ws  = (float*)d_ws;
    float* out = (float*)d_out;

    float* an   = ws + OFF_AN;
    float* qt   = ws + OFF_QT;
    float* kt   = ws + OFF_KT;
    float* vt   = ws + OFF_VT;
    float* gt   = ws + OFF_GT;
    float* ogp  = ws + OFF_OG;
    float* wz2  = ws + OFF_WZ2;
    float* shp  = ws + OFF_SH;
    float* bhp  = ws + OFF_BH;
    float* bias = ws + OFF_BIAS;

    hipLaunchKernelGGL(ln_prep_kernel, dim3(257),    dim3(256), 0, stream,
                       a, g_a, b_a, an, g_z, b_z, Wz, bz, wz2, shp, bhp);
    hipLaunchKernelGGL(qkvg_kernel,    dim3(48, 8),  dim3(256), 0, stream,
                       Wq, Wk, Wv, Wg, bg, an, qt, kt, vt, gt);
    hipLaunchKernelGGL(pairbias_kernel, dim3(2048),  dim3(256), 0, stream,
                       z, wz2, shp, bhp, bias);
    hipLaunchKernelGGL(attn_kernel,    dim3(64, 16), dim3(256), 0, stream,
                       qt, kt, vt, gt, bias, ogp);
    hipLaunchKernelGGL(out_gemm_kernel, dim3(24, 8), dim3(256), 0, stream,
                       Wo, bo, ogp, out);
}

// Round 4
// 333.991 us; speedup vs baseline: 1.0862x; 1.0464x over previous
//
#include <hip/hip_runtime.h>
#include <math.h>

#define N 512
#define CS 384
#define CZ 128
#define NH 16
#define DH 24
#define HD 384
#define NN (N*N)
#define EPS 1e-5f

// ws layout (float offsets)
#define OFF_AN   0          // a_n [N][CS]
#define OFF_QT   196608     // qT [H][N][D] (pre-scaled by 1/sqrt(24))
#define OFF_KT   393216     // kT [H][N][D]
#define OFF_VT   589824     // vT [H][N][D]
#define OFF_GT   786432     // gT [H][N][D] (sigmoid applied)
#define OFF_OG   983040     // o*g [N][HD]
#define OFF_WZ2  1179648    // g_z*Wz transposed [H][CZ]
#define OFF_SH   1181696    // [H]
#define OFF_BH   1181712    // [H]
#define OFF_BIAS 1181728    // pair bias [H][N][N]

// ---------------- fused: prep (block 256) + LayerNorm of a (blocks 0..255, 2 rows each) ----------------
__global__ void __launch_bounds__(256) ln_prep_kernel(const float* __restrict__ a, const float* __restrict__ g_a,
                                                      const float* __restrict__ b_a, float* __restrict__ an_out,
                                                      const float* __restrict__ g_z, const float* __restrict__ lnb_z,
                                                      const float* __restrict__ Wz, const float* __restrict__ bz,
                                                      float* __restrict__ wz2, float* __restrict__ sh,
                                                      float* __restrict__ bh) {
    __shared__ float ls[NH][17], lb[NH][17];   // prep block
    __shared__ float l1[4], l2[4];             // ln blocks
    const int t = threadIdx.x;
    if (blockIdx.x == 256) {
        // prep: Wz2[h][c] = g_z[c]*Wz[c][h]; Sh, Bh
        for (int i = t; i < NH * CZ; i += 256) {
            int h = i >> 7, c = i & (CZ - 1);
            wz2[h * CZ + c] = g_z[c] * Wz[c * NH + h];
        }
        int h = t >> 4, seg = t & 15;
        float s = 0.f, b = 0.f;
        #pragma unroll
        for (int i = 0; i < 8; ++i) {
            int c = seg * 8 + i;
            float w = Wz[c * NH + h];
            s += g_z[c] * w;
            b += lnb_z[c] * w;
        }
        ls[h][seg] = s; lb[h][seg] = b;
        __syncthreads();
        if (t < NH) {
            float ss = 0.f, bb = 0.f;
            #pragma unroll
            for (int i = 0; i < 16; ++i) { ss += ls[t][i]; bb += lb[t][i]; }
            sh[t] = ss;
            bh[t] = bb + bz[t];
        }
        return;
    }
    // LayerNorm: 2 rows per block (threads 0..127 -> row0, 128..255 -> row1)
    const int half = t >> 7;
    const int tr = t & 127;
    const int r = blockIdx.x * 2 + half;
    const float* row = a + r * CS;
    float x0 = row[tr], x1 = row[tr + 128], x2 = row[tr + 256];
    float s1 = x0 + x1 + x2;
    float s2 = x0 * x0 + x1 * x1 + x2 * x2;
    #pragma unroll
    for (int m = 1; m < 64; m <<= 1) {
        s1 += __shfl_xor(s1, m, 64);
        s2 += __shfl_xor(s2, m, 64);
    }
    if ((t & 63) == 0) { l1[t >> 6] = s1; l2[t >> 6] = s2; }
    __syncthreads();
    s1 = l1[half * 2] + l1[half * 2 + 1];
    s2 = l2[half * 2] + l2[half * 2 + 1];
    float mu = s1 * (1.f / CS);
    float var = s2 * (1.f / CS) - mu * mu;
    float rs = rsqrtf(var + EPS);
    float* an = an_out + r * CS;
    an[tr]       = (x0 - mu) * rs * g_a[tr]       + b_a[tr];
    an[tr + 128] = (x1 - mu) * rs * g_a[tr + 128] + b_a[tr + 128];
    an[tr + 256] = (x2 - mu) * rs * g_a[tr + 256] + b_a[tr + 256];
}

// ---------------- q,k,v,g projections (scalar-B GEMM, 8 cols/thread) — round-0 proven ----------------
// grid (48, 8), block 256. wave -> 8-col strip of [Wq|Wk|Wv|Wg]; lane -> row. 1536 waves.
__global__ void __launch_bounds__(256) qkvg_kernel(const float* __restrict__ Wq, const float* __restrict__ Wk,
                                                   const float* __restrict__ Wv, const float* __restrict__ Wg,
                                                   const float* __restrict__ bg, const float* __restrict__ an,
                                                   float* __restrict__ qt, float* __restrict__ kt,
                                                   float* __restrict__ vt, float* __restrict__ gt) {
    const int lane = threadIdx.x & 63;
    const int w = __builtin_amdgcn_readfirstlane(threadIdx.x >> 6);
    const int strip = blockIdx.x * 4 + w;     // 0..191
    const int n0 = strip * 8;
    const int sel = n0 / HD;                  // 0:q 1:k 2:v 3:g
    const int col = n0 % HD;
    const float* Wm = (sel == 0) ? Wq : (sel == 1) ? Wk : (sel == 2) ? Wv : Wg;
    const int m = blockIdx.y * 64 + lane;
    const float* arow = an + m * CS;
    float acc[8];
    #pragma unroll
    for (int j = 0; j < 8; ++j) acc[j] = 0.f;
    for (int kb = 0; kb < CS; kb += 32) {
        float4 av[8];
        #pragma unroll
        for (int i = 0; i < 8; ++i) av[i] = ((const float4*)(arow + kb))[i]; // full 128B line
        #pragma unroll
        for (int i = 0; i < 8; ++i) {
            const float* wr = Wm + (kb + i * 4) * HD + col; // wave-uniform -> s_load
            #pragma unroll
            for (int j = 0; j < 8; ++j) {
                acc[j] += av[i].x * wr[j];
                acc[j] += av[i].y * wr[HD + j];
                acc[j] += av[i].z * wr[2 * HD + j];
                acc[j] += av[i].w * wr[3 * HD + j];
            }
        }
    }
    float* dst = (sel == 0) ? qt : (sel == 1) ? kt : (sel == 2) ? vt : gt;
    if (sel == 3) {
        #pragma unroll
        for (int j = 0; j < 8; ++j) acc[j] = 1.f / (1.f + __expf(-(acc[j] + bg[col + j])));
    } else if (sel == 0) {
        #pragma unroll
        for (int j = 0; j < 8; ++j) acc[j] *= 0.20412414523193153f; // 1/sqrt(24)
    }
    #pragma unroll
    for (int j = 0; j < 8; ++j) {
        int c = col + j;
        int h = c / DH, d = c % DH;
        dst[(h * N + m) * DH + d] = acc[j];
    }
}

// ---------------- pair bias v4: 64-row tile, 4 threads/row, cheap-XOR LDS ----------------
// Block 256 = 4 waves; wave w owns heads 4w..4w+3 (uniform -> s_load weights); lane = row.
// LDS: 64 rows x 32 float4, slot = cc ^ (r&31). Compute-read addr = base ^ (cc<<4) with
// base = r*512 + (r&31)<<4 -> 1 v_xor(literal) + 1 ds_read_b128 per access, conflict-free
// (bank-starts 4*((l&31)^cc)%32 cover all 32 banks exactly 8x = the 8-clock minimum).
// 32 KB LDS + launch_bounds(256,4) -> 4 blocks/CU = 16 waves/CU (2x round-3 occupancy).
__global__ void __launch_bounds__(256, 4) pairbias_kernel(const float* __restrict__ z,
                                                          const float* __restrict__ wz2,
                                                          const float* __restrict__ sh,
                                                          const float* __restrict__ bh,
                                                          float* __restrict__ bias) {
    __shared__ float4 lz[64 * 32];   // 32 KB
    const int t = threadIdx.x;
    const int l = t & 63;                                      // row within tile
    const int w = __builtin_amdgcn_readfirstlane(t >> 6);      // head group (wave-uniform)
    const int h0 = w * 4;
    const int row0 = blockIdx.x * 64;

    // stage: 64 rows x 32 float4 = 2048 float4; 8 per thread, 4KB contiguous per wave-instr
    const float4* zsrc = (const float4*)(z + (size_t)row0 * CZ);
    #pragma unroll
    for (int i = 0; i < 8; ++i) {
        const int g4 = i * 256 + t;            // 0..2047
        float4 v = zsrc[g4];
        const int r = g4 >> 5, cc = g4 & 31;
        lz[r * 32 + (cc ^ (r & 31))] = v;
    }
    __syncthreads();

    const unsigned base = (unsigned)(l * 512 + ((l & 31) << 4));  // byte offset of row l, slot (l&31)
    const char* lzb = (const char*)lz;
    float s1 = 0.f, s2 = 0.f;
    float dots[4];
    #pragma unroll
    for (int j = 0; j < 4; ++j) dots[j] = 0.f;
    #pragma unroll
    for (int cc = 0; cc < 32; ++cc) {
        // physical slot read in order cc' = (l&31)^cc; base^(cc<<4) == addr of column cc
        float4 v = *(const float4*)(lzb + (base ^ (unsigned)(cc << 4)));
        s1 += v.x + v.y + v.z + v.w;
        s2 += v.x * v.x + v.y * v.y + v.z * v.z + v.w * v.w;
        #pragma unroll
        for (int j = 0; j < 4; ++j) {
            const float4 wv = ((const float4*)(wz2 + (h0 + j) * CZ))[cc]; // wave-uniform -> s_load
            dots[j] += v.x * wv.x + v.y * wv.y + v.z * wv.z + v.w * wv.w;
        }
    }
    const float mu = s1 * (1.f / CZ);
    const float var = s2 * (1.f / CZ) - mu * mu;
    const float rr = rsqrtf(var + EPS);
    const int row = row0 + l;
    #pragma unroll
    for (int j = 0; j < 4; ++j)
        bias[(h0 + j) * NN + row] = rr * (dots[j] - mu * sh[h0 + j]) + bh[h0 + j];
}

// ---------------- attention: 2 q per wave, 32 lanes per q over k. 4096 waves ----------------
__global__ void __launch_bounds__(256) attn_kernel(const float* __restrict__ qt, const float* __restrict__ kt,
                                                   const float* __restrict__ vt, const float* __restrict__ gt,
                                                   const float* __restrict__ bias, float* __restrict__ og) {
    const int lane = threadIdx.x & 63;
    const int w = __builtin_amdgcn_readfirstlane(threadIdx.x >> 6);
    const int qhalf = lane >> 5;     // 0/1
    const int klane = lane & 31;
    const int h = blockIdx.y;
    const int q = blockIdx.x * 8 + w * 2 + qhalf;
    const float* qT = qt + h * N * DH;
    const float* kT = kt + h * N * DH;
    const float* vT = vt + h * N * DH;

    float qv[DH];
    #pragma unroll
    for (int d6 = 0; d6 < 6; ++d6) {
        float4 t4 = ((const float4*)(qT + q * DH))[d6];
        qv[d6 * 4 + 0] = t4.x; qv[d6 * 4 + 1] = t4.y; qv[d6 * 4 + 2] = t4.z; qv[d6 * 4 + 3] = t4.w;
    }
    float sc[16];
    #pragma unroll
    for (int t = 0; t < 16; ++t) {
        const int kk = t * 32 + klane;
        const float4* kr = (const float4*)(kT + kk * DH);
        float4 k0 = kr[0], k1 = kr[1], k2 = kr[2], k3 = kr[3], k4 = kr[4], k5 = kr[5];
        float s = qv[0]*k0.x + qv[1]*k0.y + qv[2]*k0.z + qv[3]*k0.w
                + qv[4]*k1.x + qv[5]*k1.y + qv[6]*k1.z + qv[7]*k1.w
                + qv[8]*k2.x + qv[9]*k2.y + qv[10]*k2.z + qv[11]*k2.w
                + qv[12]*k3.x + qv[13]*k3.y + qv[14]*k3.z + qv[15]*k3.w
                + qv[16]*k4.x + qv[17]*k4.y + qv[18]*k4.z + qv[19]*k4.w
                + qv[20]*k5.x + qv[21]*k5.y + qv[22]*k5.z + qv[23]*k5.w;
        sc[t] = s + bias[h * NN + q * N + kk];
    }
    float mx = sc[0];
    #pragma unroll
    for (int t = 1; t < 16; ++t) mx = fmaxf(mx, sc[t]);
    #pragma unroll
    for (int m = 1; m < 32; m <<= 1) mx = fmaxf(mx, __shfl_xor(mx, m, 64));
    float sum = 0.f;
    #pragma unroll
    for (int t = 0; t < 16; ++t) { sc[t] = __expf(sc[t] - mx); sum += sc[t]; }
    #pragma unroll
    for (int m = 1; m < 32; m <<= 1) sum += __shfl_xor(sum, m, 64);
    float inv = 1.f / sum;
    #pragma unroll
    for (int t = 0; t < 16; ++t) sc[t] *= inv;
    float acc[DH];
    #pragma unroll
    for (int d = 0; d < DH; ++d) acc[d] = 0.f;
    #pragma unroll
    for (int t = 0; t < 16; ++t) {
        const int kk = t * 32 + klane;
        const float4* vr = (const float4*)(vT + kk * DH);
        float4 v0 = vr[0], v1 = vr[1], v2 = vr[2], v3 = vr[3], v4 = vr[4], v5 = vr[5];
        float p = sc[t];
        acc[0] += p*v0.x;  acc[1] += p*v0.y;  acc[2] += p*v0.z;  acc[3] += p*v0.w;
        acc[4] += p*v1.x;  acc[5] += p*v1.y;  acc[6] += p*v1.z;  acc[7] += p*v1.w;
        acc[8] += p*v2.x;  acc[9] += p*v2.y;  acc[10] += p*v2.z; acc[11] += p*v2.w;
        acc[12] += p*v3.x; acc[13] += p*v3.y; acc[14] += p*v3.z; acc[15] += p*v3.w;
        acc[16] += p*v4.x; acc[17] += p*v4.y; acc[18] += p*v4.z; acc[19] += p*v4.w;
        acc[20] += p*v5.x; acc[21] += p*v5.y; acc[22] += p*v5.z; acc[23] += p*v5.w;
    }
    #pragma unroll
    for (int m = 1; m < 32; m <<= 1) {
        #pragma unroll
        for (int d = 0; d < DH; ++d) acc[d] += __shfl_xor(acc[d], m, 64);
    }
    float o = 0.f;
    #pragma unroll
    for (int d = 0; d < DH; ++d) o = (klane == d) ? acc[d] : o;
    if (klane < DH) {
        float g = gt[h * N * DH + q * DH + klane];
        og[q * HD + h * DH + klane] = o * g;
    }
}

// ---------------- out = og @ Wo + bo (4 cols/thread, 768 waves) — round-0 proven ----------------
__global__ void __launch_bounds__(256) out_gemm_kernel(const float* __restrict__ Wo, const float* __restrict__ bo,
                                                       const float* __restrict__ og, float* __restrict__ out) {
    const int lane = threadIdx.x & 63;
    const int w = __builtin_amdgcn_readfirstlane(threadIdx.x >> 6);
    const int strip = blockIdx.x * 4 + w;  // 0..95
    const int c0 = strip * 4;
    const int m = blockIdx.y * 64 + lane;
    const float* orow = og + m * HD;
    float acc[4];
    #pragma unroll
    for (int j = 0; j < 4; ++j) acc[j] = 0.f;
    for (int kb = 0; kb < HD; kb += 32) {
        float4 av[8];
        #pragma unroll
        for (int i = 0; i < 8; ++i) av[i] = ((const float4*)(orow + kb))[i];
        #pragma unroll
        for (int i = 0; i < 8; ++i) {
            const float* wr = Wo + (kb + i * 4) * CS + c0; // uniform -> s_load
            #pragma unroll
            for (int j = 0; j < 4; ++j) {
                acc[j] += av[i].x * wr[j];
                acc[j] += av[i].y * wr[CS + j];
                acc[j] += av[i].z * wr[2 * CS + j];
                acc[j] += av[i].w * wr[3 * CS + j];
            }
        }
    }
    #pragma unroll
    for (int j = 0; j < 4; ++j) out[m * CS + c0 + j] = acc[j] + bo[c0 + j];
}

extern "C" void kernel_launch(void* const* d_in, const int* in_sizes, int n_in,
                              void* d_out, int out_size, void* d_ws, size_t ws_size,
                              hipStream_t stream) {
    const float* a    = (const float*)d_in[0];
    const float* z    = (const float*)d_in[1];
    const float* g_a  = (const float*)d_in[2];
    const float* b_a  = (const float*)d_in[3];
    const float* g_z  = (const float*)d_in[4];
    const float* b_z  = (const float*)d_in[5];
    const float* Wz   = (const float*)d_in[6];
    const float* bz   = (const float*)d_in[7];
    const float* Wq   = (const float*)d_in[8];
    const float* Wk   = (const float*)d_in[9];
    const float* Wv   = (const float*)d_in[10];
    const float* Wg   = (const float*)d_in[11];
    const float* bg   = (const float*)d_in[12];
    const float* Wo   = (const float*)d_in[13];
    const float* bo   = (const float*)d_in[14];
    float* ws  = (float*)d_ws;
    float* out = (float*)d_out;

    float* an   = ws + OFF_AN;
    float* qt   = ws + OFF_QT;
    float* kt   = ws + OFF_KT;
    float* vt   = ws + OFF_VT;
    float* gt   = ws + OFF_GT;
    float* ogp  = ws + OFF_OG;
    float* wz2  = ws + OFF_WZ2;
    float* shp  = ws + OFF_SH;
    float* bhp  = ws + OFF_BH;
    float* bias = ws + OFF_BIAS;

    hipLaunchKernelGGL(ln_prep_kernel, dim3(257),    dim3(256), 0, stream,
                       a, g_a, b_a, an, g_z, b_z, Wz, bz, wz2, shp, bhp);
    hipLaunchKernelGGL(qkvg_kernel,    dim3(48, 8),  dim3(256), 0, stream,
                       Wq, Wk, Wv, Wg, bg, an, qt, kt, vt, gt);
    hipLaunchKernelGGL(pairbias_kernel, dim3(4096),  dim3(256), 0, stream,
                       z, wz2, shp, bhp, bias);
    hipLaunchKernelGGL(attn_kernel,    dim3(64, 16), dim3(256), 0, stream,
                       qt, kt, vt, gt, bias, ogp);
    hipLaunchKernelGGL(out_gemm_kernel, dim3(24, 8), dim3(256), 0, stream,
                       Wo, bo, ogp, out);
}